// Round 3
// baseline (487.550 us; speedup 1.0000x reference)
//
#include <hip/hip_runtime.h>
#include <hip/hip_bf16.h>

typedef unsigned short ushort_t;
typedef __bf16 bf16x8 __attribute__((ext_vector_type(8)));
typedef float f32x4 __attribute__((ext_vector_type(4)));

#define N_TOK 2048
#define DH    1024
#define FF    512
#define SFF   2816
#define NE    16

#define BM 128
#define BN 64
#define BK 64
#define LDK 72   // 64 + 8 pad (ushorts); row = 144 B, 16B-aligned

__device__ __forceinline__ ushort_t f2bf(float f) {
  unsigned int x = __float_as_uint(f);
  unsigned int lsb = (x >> 16) & 1u;
  x += 0x7fffu + lsb;            // RNE; finite inputs
  return (ushort_t)(x >> 16);
}

__device__ __forceinline__ void cvt8(const float* __restrict__ p, ushort_t* __restrict__ o) {
  float4 a = *(const float4*)p;
  float4 b = *(const float4*)(p + 4);
  o[0] = f2bf(a.x); o[1] = f2bf(a.y); o[2] = f2bf(a.z); o[3] = f2bf(a.w);
  o[4] = f2bf(b.x); o[5] = f2bf(b.y); o[6] = f2bf(b.z); o[7] = f2bf(b.w);
}

// ---------------- zero acc ----------------
__global__ void zero_acc_kernel(float4* __restrict__ acc) {
  acc[(size_t)blockIdx.x * 256 + threadIdx.x] = make_float4(0.f, 0.f, 0.f, 0.f);
}

// ---------------- router (fp32): logits, top-2, renorm, shared sigmoid gate ----------------
__global__ void router_kernel(const float* __restrict__ X, const float* __restrict__ GW,
                              const float* __restrict__ SGW,
                              int* __restrict__ sel, float* __restrict__ wtk,
                              float* __restrict__ sgate) {
  int wave = threadIdx.x >> 6, lane = threadIdx.x & 63;
  int n = blockIdx.x * 4 + wave;
  const float* x = X + (size_t)n * DH;
  int e = lane & 15, s = lane >> 4;
  const float* gw = GW + (size_t)e * DH;
  float lg = 0.f;
  for (int i = 0; i < 256; ++i) {
    int d = s * 256 + i;
    lg += x[d] * gw[d];
  }
  lg += __shfl_down(lg, 32);
  lg += __shfl_down(lg, 16);          // lanes 0..15 hold logits[e]

  float gd = 0.f;
  #pragma unroll
  for (int i = 0; i < 16; ++i) {
    int d = lane * 16 + i;
    gd += x[d] * SGW[d];
  }
  #pragma unroll
  for (int off = 32; off >= 1; off >>= 1) gd += __shfl_down(gd, off);

  float l[16];
  #pragma unroll
  for (int i = 0; i < 16; ++i) l[i] = __shfl(lg, i);

  if (lane == 0) {
    int i1 = 0; float v1 = l[0];
    #pragma unroll
    for (int i = 1; i < 16; ++i) if (l[i] > v1) { v1 = l[i]; i1 = i; }
    int i2 = -1; float v2 = -1e30f;
    #pragma unroll
    for (int i = 0; i < 16; ++i) { if (i == i1) continue; if (l[i] > v2) { v2 = l[i]; i2 = i; } }
    float p2 = __expf(v2 - v1);          // softmax denom cancels in renorm
    float inv = 1.f / (1.f + p2);
    sel[n * 2 + 0] = i1; sel[n * 2 + 1] = i2;
    wtk[n * 2 + 0] = inv; wtk[n * 2 + 1] = p2 * inv;
    sgate[n] = 1.f / (1.f + __expf(-gd));
  }
}

// ---------------- single-block scatter: compact per-expert token lists ----------------
__global__ void scatter_kernel(const int* __restrict__ sel, const float* __restrict__ wtk,
                               int* __restrict__ toks, float* __restrict__ wts,
                               int* __restrict__ offs) {
  __shared__ int cnt[NE], bas[NE];
  int t = threadIdx.x;
  if (t < NE) cnt[t] = 0;
  __syncthreads();
  for (int i = t; i < N_TOK * 2; i += 256) atomicAdd(&cnt[sel[i]], 1);
  __syncthreads();
  if (t == 0) {
    int s = 0;
    for (int e = 0; e < NE; ++e) { bas[e] = s; offs[e] = s; s += cnt[e]; }
    offs[NE] = s;
  }
  __syncthreads();
  if (t < NE) cnt[t] = 0;
  __syncthreads();
  for (int i = t; i < N_TOK * 2; i += 256) {
    int e = sel[i];
    int p = atomicAdd(&cnt[e], 1);
    int slot = bas[e] + p;
    toks[slot] = i >> 1;
    wts[slot]  = wtk[i];
  }
}

// ---------------- expert gate_up + SwiGLU ----------------
// A: gathered fp32 x rows -> bf16 LDS. B: wgu[e] = [1024 k][1024 n] fp32,
// transposed-staged to bf16 LDS [n][k]. H[slot][col] = silu(g)*u (bf16), stride FF.
__global__ __launch_bounds__(256, 2) void gateup_expert_kernel(
    const float* __restrict__ X, const float* __restrict__ WGU,
    ushort_t* __restrict__ H, const int* __restrict__ toks,
    const int* __restrict__ offs) {
  __shared__ __align__(16) ushort_t As[BM][LDK];
  __shared__ __align__(16) ushort_t Bgs[BN][LDK];
  __shared__ __align__(16) ushort_t Bus[BN][LDK];
  const int K = DH;

  int e = blockIdx.z;
  int base = offs[e], M = offs[e + 1] - base;
  int m0 = blockIdx.y * BM;
  if (m0 >= M) return;
  int n0 = blockIdx.x * BN;
  const float* W = WGU + (size_t)e * DH * (2 * FF);

  int t = threadIdx.x;
  int wave = t >> 6, lane = t & 63;
  int wm = wave & 1, wn = wave >> 1;
  int qd = lane >> 4, l16 = lane & 15;
  int sr = t >> 3, sc = (t & 7) * 8;
  int tn = t & 63, tk = (t >> 6) * 16;

  const float* arow[4];
  #pragma unroll
  for (int p = 0; p < 4; ++p) {
    int m = m0 + sr + 32 * p;
    int mm = m < M ? m : (M - 1);
    arow[p] = X + (size_t)toks[base + mm] * K + sc;
  }

  f32x4 accg[4][2], accu[4][2];
  #pragma unroll
  for (int i = 0; i < 4; ++i)
    #pragma unroll
    for (int j = 0; j < 2; ++j) {
      accg[i][j] = (f32x4){0.f, 0.f, 0.f, 0.f};
      accu[i][j] = (f32x4){0.f, 0.f, 0.f, 0.f};
    }

  for (int k0 = 0; k0 < K; k0 += BK) {
    #pragma unroll
    for (int p = 0; p < 4; ++p) {
      ushort_t tmp[8];
      cvt8(arow[p] + k0, tmp);
      *(uint4*)&As[sr + 32 * p][sc] = *(uint4*)tmp;
    }
    {
      const float* wk = W + (size_t)(k0 + tk) * (2 * FF) + n0 + tn;
      ushort_t gtmp[16], utmp[16];
      #pragma unroll
      for (int j = 0; j < 16; ++j) {
        gtmp[j] = f2bf(wk[(size_t)j * (2 * FF)]);
        utmp[j] = f2bf(wk[(size_t)j * (2 * FF) + FF]);
      }
      *(uint4*)&Bgs[tn][tk]     = *(uint4*)&gtmp[0];
      *(uint4*)&Bgs[tn][tk + 8] = *(uint4*)&gtmp[8];
      *(uint4*)&Bus[tn][tk]     = *(uint4*)&utmp[0];
      *(uint4*)&Bus[tn][tk + 8] = *(uint4*)&utmp[8];
    }
    __syncthreads();
    #pragma unroll
    for (int ks = 0; ks < 2; ++ks) {
      int kk = ks * 32 + qd * 8;
      bf16x8 af[4], bgf[2], buf[2];
      #pragma unroll
      for (int i = 0; i < 4; ++i)
        af[i] = *(const bf16x8*)&As[wm * 64 + i * 16 + l16][kk];
      #pragma unroll
      for (int j = 0; j < 2; ++j) {
        bgf[j] = *(const bf16x8*)&Bgs[wn * 32 + j * 16 + l16][kk];
        buf[j] = *(const bf16x8*)&Bus[wn * 32 + j * 16 + l16][kk];
      }
      #pragma unroll
      for (int i = 0; i < 4; ++i)
        #pragma unroll
        for (int j = 0; j < 2; ++j) {
          accg[i][j] = __builtin_amdgcn_mfma_f32_16x16x32_bf16(af[i], bgf[j], accg[i][j], 0, 0, 0);
          accu[i][j] = __builtin_amdgcn_mfma_f32_16x16x32_bf16(af[i], buf[j], accu[i][j], 0, 0, 0);
        }
    }
    __syncthreads();
  }

  #pragma unroll
  for (int i = 0; i < 4; ++i)
    #pragma unroll
    for (int r = 0; r < 4; ++r) {
      int m = m0 + wm * 64 + i * 16 + qd * 4 + r;
      if (m >= M) continue;
      #pragma unroll
      for (int j = 0; j < 2; ++j) {
        float g = accg[i][j][r], u = accu[i][j][r];
        float h = g / (1.f + __expf(-g)) * u;
        int col = n0 + wn * 32 + j * 16 + l16;
        H[(size_t)(base + m) * FF + col] = f2bf(h);
      }
    }
}

// ---------------- shared gate_up + SwiGLU (NT: swg/swu are fp32 [N][K]) ----------------
__global__ __launch_bounds__(256, 2) void gateup_shared_kernel(
    const float* __restrict__ X, const float* __restrict__ Bg,
    const float* __restrict__ Bu, ushort_t* __restrict__ H) {
  __shared__ __align__(16) ushort_t As[BM][LDK];
  __shared__ __align__(16) ushort_t Bgs[BN][LDK];
  __shared__ __align__(16) ushort_t Bus[BN][LDK];
  const int K = DH;

  int m0 = blockIdx.y * BM;
  int n0 = blockIdx.x * BN;
  int t = threadIdx.x;
  int wave = t >> 6, lane = t & 63;
  int wm = wave & 1, wn = wave >> 1;
  int qd = lane >> 4, l16 = lane & 15;
  int sr = t >> 3, sc = (t & 7) * 8;

  f32x4 accg[4][2], accu[4][2];
  #pragma unroll
  for (int i = 0; i < 4; ++i)
    #pragma unroll
    for (int j = 0; j < 2; ++j) {
      accg[i][j] = (f32x4){0.f, 0.f, 0.f, 0.f};
      accu[i][j] = (f32x4){0.f, 0.f, 0.f, 0.f};
    }

  for (int k0 = 0; k0 < K; k0 += BK) {
    #pragma unroll
    for (int p = 0; p < 4; ++p) {
      ushort_t tmp[8];
      cvt8(X + (size_t)(m0 + sr + 32 * p) * K + k0 + sc, tmp);
      *(uint4*)&As[sr + 32 * p][sc] = *(uint4*)tmp;
    }
    #pragma unroll
    for (int p = 0; p < 2; ++p) {
      int n = n0 + sr + 32 * p;
      ushort_t tg[8], tu[8];
      cvt8(Bg + (size_t)n * K + k0 + sc, tg);
      cvt8(Bu + (size_t)n * K + k0 + sc, tu);
      *(uint4*)&Bgs[sr + 32 * p][sc] = *(uint4*)tg;
      *(uint4*)&Bus[sr + 32 * p][sc] = *(uint4*)tu;
    }
    __syncthreads();
    #pragma unroll
    for (int ks = 0; ks < 2; ++ks) {
      int kk = ks * 32 + qd * 8;
      bf16x8 af[4], bgf[2], buf[2];
      #pragma unroll
      for (int i = 0; i < 4; ++i)
        af[i] = *(const bf16x8*)&As[wm * 64 + i * 16 + l16][kk];
      #pragma unroll
      for (int j = 0; j < 2; ++j) {
        bgf[j] = *(const bf16x8*)&Bgs[wn * 32 + j * 16 + l16][kk];
        buf[j] = *(const bf16x8*)&Bus[wn * 32 + j * 16 + l16][kk];
      }
      #pragma unroll
      for (int i = 0; i < 4; ++i)
        #pragma unroll
        for (int j = 0; j < 2; ++j) {
          accg[i][j] = __builtin_amdgcn_mfma_f32_16x16x32_bf16(af[i], bgf[j], accg[i][j], 0, 0, 0);
          accu[i][j] = __builtin_amdgcn_mfma_f32_16x16x32_bf16(af[i], buf[j], accu[i][j], 0, 0, 0);
        }
    }
    __syncthreads();
  }

  #pragma unroll
  for (int i = 0; i < 4; ++i)
    #pragma unroll
    for (int r = 0; r < 4; ++r) {
      int m = m0 + wm * 64 + i * 16 + qd * 4 + r;
      #pragma unroll
      for (int j = 0; j < 2; ++j) {
        float g = accg[i][j][r], u = accu[i][j][r];
        float h = g / (1.f + __expf(-g)) * u;
        int col = n0 + wn * 32 + j * 16 + l16;
        H[(size_t)m * SFF + col] = f2bf(h);
      }
    }
}

// ---------------- expert down: acc[tok] += w * (h @ Wd) ----------------
// A: hx bf16. B: wdn[e] fp32 [512 k][1024 n], transposed-staged to bf16 LDS.
__global__ __launch_bounds__(256, 2) void down_expert_kernel(
    const ushort_t* __restrict__ HX, const float* __restrict__ WDN,
    float* __restrict__ acc, const int* __restrict__ toks,
    const float* __restrict__ wts, const int* __restrict__ offs) {
  __shared__ __align__(16) ushort_t As[BM][LDK];
  __shared__ __align__(16) ushort_t Bs[BN][LDK];
  const int K = FF;

  int e = blockIdx.z;
  int base = offs[e], M = offs[e + 1] - base;
  int m0 = blockIdx.y * BM;
  if (m0 >= M) return;
  int n0 = blockIdx.x * BN;
  const float* W = WDN + (size_t)e * FF * DH;
  const ushort_t* A = HX + (size_t)base * K;

  int t = threadIdx.x;
  int wave = t >> 6, lane = t & 63;
  int wm = wave & 1, wn = wave >> 1;
  int qd = lane >> 4, l16 = lane & 15;
  int sr = t >> 3, sc = (t & 7) * 8;
  int tn = t & 63, tk = (t >> 6) * 16;

  f32x4 c[4][2];
  #pragma unroll
  for (int i = 0; i < 4; ++i)
    #pragma unroll
    for (int j = 0; j < 2; ++j) c[i][j] = (f32x4){0.f, 0.f, 0.f, 0.f};

  for (int k0 = 0; k0 < K; k0 += BK) {
    #pragma unroll
    for (int p = 0; p < 4; ++p)
      *(uint4*)&As[sr + 32 * p][sc] =
          *(const uint4*)(A + (size_t)(m0 + sr + 32 * p) * K + k0 + sc);
    {
      const float* wk = W + (size_t)(k0 + tk) * DH + n0 + tn;
      ushort_t btmp[16];
      #pragma unroll
      for (int j = 0; j < 16; ++j) btmp[j] = f2bf(wk[(size_t)j * DH]);
      *(uint4*)&Bs[tn][tk]     = *(uint4*)&btmp[0];
      *(uint4*)&Bs[tn][tk + 8] = *(uint4*)&btmp[8];
    }
    __syncthreads();
    #pragma unroll
    for (int ks = 0; ks < 2; ++ks) {
      int kk = ks * 32 + qd * 8;
      bf16x8 af[4], bf[2];
      #pragma unroll
      for (int i = 0; i < 4; ++i)
        af[i] = *(const bf16x8*)&As[wm * 64 + i * 16 + l16][kk];
      #pragma unroll
      for (int j = 0; j < 2; ++j)
        bf[j] = *(const bf16x8*)&Bs[wn * 32 + j * 16 + l16][kk];
      #pragma unroll
      for (int i = 0; i < 4; ++i)
        #pragma unroll
        for (int j = 0; j < 2; ++j)
          c[i][j] = __builtin_amdgcn_mfma_f32_16x16x32_bf16(af[i], bf[j], c[i][j], 0, 0, 0);
    }
    __syncthreads();
  }

  #pragma unroll
  for (int i = 0; i < 4; ++i)
    #pragma unroll
    for (int r = 0; r < 4; ++r) {
      int m = m0 + wm * 64 + i * 16 + qd * 4 + r;
      if (m >= M) continue;
      int tok = toks[base + m];
      float w = wts[base + m];
      #pragma unroll
      for (int j = 0; j < 2; ++j) {
        int n = n0 + wn * 32 + j * 16 + l16;
        atomicAdd(&acc[(size_t)tok * DH + n], c[i][j][r] * w);
      }
    }
}

// ---------------- shared down + combine (NT: swd fp32 [1024][2816]); fp32 out ----------------
__global__ __launch_bounds__(256, 2) void down_shared_kernel(
    const ushort_t* __restrict__ HS, const float* __restrict__ Bp,
    const float* __restrict__ acc, float* __restrict__ out,
    const float* __restrict__ sgate) {
  __shared__ __align__(16) ushort_t As[BM][LDK];
  __shared__ __align__(16) ushort_t Bs[BN][LDK];
  const int K = SFF;

  int m0 = blockIdx.y * BM;
  int n0 = blockIdx.x * BN;
  int t = threadIdx.x;
  int wave = t >> 6, lane = t & 63;
  int wm = wave & 1, wn = wave >> 1;
  int qd = lane >> 4, l16 = lane & 15;
  int sr = t >> 3, sc = (t & 7) * 8;

  f32x4 c[4][2];
  #pragma unroll
  for (int i = 0; i < 4; ++i)
    #pragma unroll
    for (int j = 0; j < 2; ++j) c[i][j] = (f32x4){0.f, 0.f, 0.f, 0.f};

  for (int k0 = 0; k0 < K; k0 += BK) {
    #pragma unroll
    for (int p = 0; p < 4; ++p)
      *(uint4*)&As[sr + 32 * p][sc] =
          *(const uint4*)(HS + (size_t)(m0 + sr + 32 * p) * K + k0 + sc);
    #pragma unroll
    for (int p = 0; p < 2; ++p) {
      ushort_t tb[8];
      cvt8(Bp + (size_t)(n0 + sr + 32 * p) * K + k0 + sc, tb);
      *(uint4*)&Bs[sr + 32 * p][sc] = *(uint4*)tb;
    }
    __syncthreads();
    #pragma unroll
    for (int ks = 0; ks < 2; ++ks) {
      int kk = ks * 32 + qd * 8;
      bf16x8 af[4], bf[2];
      #pragma unroll
      for (int i = 0; i < 4; ++i)
        af[i] = *(const bf16x8*)&As[wm * 64 + i * 16 + l16][kk];
      #pragma unroll
      for (int j = 0; j < 2; ++j)
        bf[j] = *(const bf16x8*)&Bs[wn * 32 + j * 16 + l16][kk];
      #pragma unroll
      for (int i = 0; i < 4; ++i)
        #pragma unroll
        for (int j = 0; j < 2; ++j)
          c[i][j] = __builtin_amdgcn_mfma_f32_16x16x32_bf16(af[i], bf[j], c[i][j], 0, 0, 0);
    }
    __syncthreads();
  }

  #pragma unroll
  for (int i = 0; i < 4; ++i)
    #pragma unroll
    for (int r = 0; r < 4; ++r) {
      int m = m0 + wm * 64 + i * 16 + qd * 4 + r;
      float sg = sgate[m];
      #pragma unroll
      for (int j = 0; j < 2; ++j) {
        int n = n0 + wn * 32 + j * 16 + l16;
        out[(size_t)m * DH + n] = c[i][j][r] * sg + acc[(size_t)m * DH + n];
      }
    }
}

// ---------------- launcher ----------------
extern "C" void kernel_launch(void* const* d_in, const int* in_sizes, int n_in,
                              void* d_out, int out_size, void* d_ws, size_t ws_size,
                              hipStream_t stream) {
  const float* x    = (const float*)d_in[0];   // [2048,1024]
  const float* gw   = (const float*)d_in[1];   // [16,1024]
  const float* wgu  = (const float*)d_in[2];   // [16,1024,1024]
  const float* wdn  = (const float*)d_in[3];   // [16,512,1024]
  const float* swg  = (const float*)d_in[4];   // [2816,1024]
  const float* swu  = (const float*)d_in[5];   // [2816,1024]
  const float* swd  = (const float*)d_in[6];   // [1024,2816]
  const float* sgw  = (const float*)d_in[7];   // [1,1024]
  float* out = (float*)d_out;

  char* ws = (char*)d_ws;
  constexpr size_t OFF_ACC  = 0;                                       // 8,388,608 B
  constexpr size_t OFF_HS   = OFF_ACC + (size_t)N_TOK * DH * 4;        // +11,534,336
  constexpr size_t OFF_HX   = OFF_HS  + (size_t)N_TOK * SFF * 2;       // +4,325,376
  constexpr size_t OFF_TOK  = OFF_HX  + (size_t)4224 * FF * 2;
  constexpr size_t OFF_WTS  = OFF_TOK + 4224 * 4;
  constexpr size_t OFF_OFFS = OFF_WTS + 4224 * 4;
  constexpr size_t OFF_SEL  = OFF_OFFS + 32 * 4;
  constexpr size_t OFF_WTK  = OFF_SEL + 4096 * 4;
  constexpr size_t OFF_SG   = OFF_WTK + 4096 * 4;                      // end ~24.3 MB

  float*    acc   = (float*)(ws + OFF_ACC);
  ushort_t* hs    = (ushort_t*)(ws + OFF_HS);
  ushort_t* hx    = (ushort_t*)(ws + OFF_HX);
  int*      toks  = (int*)(ws + OFF_TOK);
  float*    wts   = (float*)(ws + OFF_WTS);
  int*      offs  = (int*)(ws + OFF_OFFS);
  int*      sel   = (int*)(ws + OFF_SEL);
  float*    wtk   = (float*)(ws + OFF_WTK);
  float*    sgate = (float*)(ws + OFF_SG);

  zero_acc_kernel<<<2048, 256, 0, stream>>>((float4*)acc);
  router_kernel<<<N_TOK / 4, 256, 0, stream>>>(x, gw, sgw, sel, wtk, sgate);
  scatter_kernel<<<1, 256, 0, stream>>>(sel, wtk, toks, wts, offs);
  gateup_expert_kernel<<<dim3(FF / BN, N_TOK / BM, NE), 256, 0, stream>>>(
      x, wgu, hx, toks, offs);
  gateup_shared_kernel<<<dim3(SFF / BN, N_TOK / BM, 1), 256, 0, stream>>>(
      x, swg, swu, hs);
  down_expert_kernel<<<dim3(DH / BN, N_TOK / BM, NE), 256, 0, stream>>>(
      hx, wdn, acc, toks, wts, offs);
  down_shared_kernel<<<dim3(DH / BN, N_TOK / BM, 1), 256, 0, stream>>>(
      hs, swd, acc, out, sgate);
}

// Round 4
// 410.257 us; speedup vs baseline: 1.1884x; 1.1884x over previous
//
#include <hip/hip_runtime.h>
#include <hip/hip_bf16.h>

typedef unsigned short ushort_t;
typedef __bf16 bf16x8 __attribute__((ext_vector_type(8)));
typedef float f32x4 __attribute__((ext_vector_type(4)));

#define N_TOK 2048
#define DH    1024
#define FF    512
#define SFF   2816
#define NE    16

#define BM 128
#define BN 64
#define BK 64
#define LDK 72   // 64 + 8 pad (ushorts); row = 144 B; 2-way bank alias = free

__device__ __forceinline__ ushort_t f2bf(float f) {
  unsigned int x = __float_as_uint(f);
  unsigned int lsb = (x >> 16) & 1u;
  x += 0x7fffu + lsb;            // RNE; finite inputs
  return (ushort_t)(x >> 16);
}

__device__ __forceinline__ uint4 cvt8v(const float4 a, const float4 b) {
  union { ushort_t u[8]; uint4 v; } r;
  r.u[0] = f2bf(a.x); r.u[1] = f2bf(a.y); r.u[2] = f2bf(a.z); r.u[3] = f2bf(a.w);
  r.u[4] = f2bf(b.x); r.u[5] = f2bf(b.y); r.u[6] = f2bf(b.z); r.u[7] = f2bf(b.w);
  return r.v;
}

// ---------------- zero acc ----------------
__global__ void zero_acc_kernel(float4* __restrict__ acc) {
  acc[(size_t)blockIdx.x * 256 + threadIdx.x] = make_float4(0.f, 0.f, 0.f, 0.f);
}

// ---------------- final epilogue: out = acc ----------------
__global__ void out_epilogue_kernel(const float4* __restrict__ acc, float4* __restrict__ out) {
  size_t i = (size_t)blockIdx.x * 256 + threadIdx.x;
  out[i] = acc[i];
}

// ---------------- router (fp32): logits, top-2, renorm, shared sigmoid gate ----------------
__global__ void router_kernel(const float* __restrict__ X, const float* __restrict__ GW,
                              const float* __restrict__ SGW,
                              int* __restrict__ sel, float* __restrict__ wtk,
                              float* __restrict__ sgate) {
  int wave = threadIdx.x >> 6, lane = threadIdx.x & 63;
  int n = blockIdx.x * 4 + wave;
  const float* x = X + (size_t)n * DH;
  int e = lane & 15, s = lane >> 4;
  const float* gw = GW + (size_t)e * DH;
  float lg = 0.f;
  for (int i = 0; i < 256; ++i) {
    int d = s * 256 + i;
    lg += x[d] * gw[d];
  }
  lg += __shfl_down(lg, 32);
  lg += __shfl_down(lg, 16);          // lanes 0..15 hold logits[e]

  float gd = 0.f;
  #pragma unroll
  for (int i = 0; i < 16; ++i) {
    int d = lane * 16 + i;
    gd += x[d] * SGW[d];
  }
  #pragma unroll
  for (int off = 32; off >= 1; off >>= 1) gd += __shfl_down(gd, off);

  float l[16];
  #pragma unroll
  for (int i = 0; i < 16; ++i) l[i] = __shfl(lg, i);

  if (lane == 0) {
    int i1 = 0; float v1 = l[0];
    #pragma unroll
    for (int i = 1; i < 16; ++i) if (l[i] > v1) { v1 = l[i]; i1 = i; }
    int i2 = -1; float v2 = -1e30f;
    #pragma unroll
    for (int i = 0; i < 16; ++i) { if (i == i1) continue; if (l[i] > v2) { v2 = l[i]; i2 = i; } }
    float p2 = __expf(v2 - v1);          // softmax denom cancels in renorm
    float inv = 1.f / (1.f + p2);
    sel[n * 2 + 0] = i1; sel[n * 2 + 1] = i2;
    wtk[n * 2 + 0] = inv; wtk[n * 2 + 1] = p2 * inv;
    sgate[n] = 1.f / (1.f + __expf(-gd));
  }
}

// ---------------- single-block scatter: compact per-expert token lists ----------------
__global__ void scatter_kernel(const int* __restrict__ sel, const float* __restrict__ wtk,
                               int* __restrict__ toks, float* __restrict__ wts,
                               int* __restrict__ offs) {
  __shared__ int cnt[NE], bas[NE];
  int t = threadIdx.x;
  if (t < NE) cnt[t] = 0;
  __syncthreads();
  for (int i = t; i < N_TOK * 2; i += 256) atomicAdd(&cnt[sel[i]], 1);
  __syncthreads();
  if (t == 0) {
    int s = 0;
    for (int e = 0; e < NE; ++e) { bas[e] = s; offs[e] = s; s += cnt[e]; }
    offs[NE] = s;
  }
  __syncthreads();
  if (t < NE) cnt[t] = 0;
  __syncthreads();
  for (int i = t; i < N_TOK * 2; i += 256) {
    int e = sel[i];
    int p = atomicAdd(&cnt[e], 1);
    int slot = bas[e] + p;
    toks[slot] = i >> 1;
    wts[slot]  = wtk[i];
  }
}

// ---------------- expert gate_up + SwiGLU (register-prefetch pipeline) ----------------
__global__ __launch_bounds__(256, 2) void gateup_expert_kernel(
    const float* __restrict__ X, const float* __restrict__ WGU,
    ushort_t* __restrict__ H, const int* __restrict__ toks,
    const int* __restrict__ offs) {
  __shared__ __align__(16) ushort_t As[BM][LDK];
  __shared__ __align__(16) ushort_t Bgs[BN][LDK];
  __shared__ __align__(16) ushort_t Bus[BN][LDK];
  const int K = DH, NT = K / BK;

  int e = blockIdx.z;
  int base = offs[e], M = offs[e + 1] - base;
  int m0 = blockIdx.y * BM;
  if (m0 >= M) return;
  int n0 = blockIdx.x * BN;
  const float* W = WGU + (size_t)e * DH * (2 * FF);

  int t = threadIdx.x;
  int wave = t >> 6, lane = t & 63;
  int wm = wave & 1, wn = wave >> 1;
  int qd = lane >> 4, l16 = lane & 15;
  int sr = t >> 3, sc = (t & 7) * 8;
  int tn = t & 63, tk = (t >> 6) * 16;

  const float* arow[4];
  #pragma unroll
  for (int p = 0; p < 4; ++p) {
    int m = m0 + sr + 32 * p;
    int mm = m < M ? m : (M - 1);
    arow[p] = X + (size_t)toks[base + mm] * K + sc;
  }
  const float* wkb = W + (size_t)tk * (2 * FF) + n0 + tn;

  float4 ar[4][2];
  float bgr[16], bur[16];
  #pragma unroll
  for (int p = 0; p < 4; ++p) {
    ar[p][0] = *(const float4*)(arow[p]);
    ar[p][1] = *(const float4*)(arow[p] + 4);
  }
  #pragma unroll
  for (int j = 0; j < 16; ++j) {
    bgr[j] = wkb[(size_t)j * (2 * FF)];
    bur[j] = wkb[(size_t)j * (2 * FF) + FF];
  }

  f32x4 accg[4][2], accu[4][2];
  #pragma unroll
  for (int i = 0; i < 4; ++i)
    #pragma unroll
    for (int j = 0; j < 2; ++j) {
      accg[i][j] = (f32x4){0.f, 0.f, 0.f, 0.f};
      accu[i][j] = (f32x4){0.f, 0.f, 0.f, 0.f};
    }

  for (int kt = 0; kt < NT; ++kt) {
    #pragma unroll
    for (int p = 0; p < 4; ++p)
      *(uint4*)&As[sr + 32 * p][sc] = cvt8v(ar[p][0], ar[p][1]);
    {
      union { ushort_t u[8]; uint4 v; } g0, g1, u0, u1;
      #pragma unroll
      for (int j = 0; j < 8; ++j) {
        g0.u[j] = f2bf(bgr[j]); g1.u[j] = f2bf(bgr[8 + j]);
        u0.u[j] = f2bf(bur[j]); u1.u[j] = f2bf(bur[8 + j]);
      }
      *(uint4*)&Bgs[tn][tk]     = g0.v;
      *(uint4*)&Bgs[tn][tk + 8] = g1.v;
      *(uint4*)&Bus[tn][tk]     = u0.v;
      *(uint4*)&Bus[tn][tk + 8] = u1.v;
    }
    __syncthreads();
    if (kt + 1 < NT) {
      int ko = (kt + 1) * BK;
      #pragma unroll
      for (int p = 0; p < 4; ++p) {
        ar[p][0] = *(const float4*)(arow[p] + ko);
        ar[p][1] = *(const float4*)(arow[p] + ko + 4);
      }
      const float* wk = wkb + (size_t)ko * (2 * FF);
      #pragma unroll
      for (int j = 0; j < 16; ++j) {
        bgr[j] = wk[(size_t)j * (2 * FF)];
        bur[j] = wk[(size_t)j * (2 * FF) + FF];
      }
    }
    #pragma unroll
    for (int ks = 0; ks < 2; ++ks) {
      int kk = ks * 32 + qd * 8;
      bf16x8 af[4], bgf[2], buf[2];
      #pragma unroll
      for (int i = 0; i < 4; ++i)
        af[i] = *(const bf16x8*)&As[wm * 64 + i * 16 + l16][kk];
      #pragma unroll
      for (int j = 0; j < 2; ++j) {
        bgf[j] = *(const bf16x8*)&Bgs[wn * 32 + j * 16 + l16][kk];
        buf[j] = *(const bf16x8*)&Bus[wn * 32 + j * 16 + l16][kk];
      }
      #pragma unroll
      for (int i = 0; i < 4; ++i)
        #pragma unroll
        for (int j = 0; j < 2; ++j) {
          accg[i][j] = __builtin_amdgcn_mfma_f32_16x16x32_bf16(af[i], bgf[j], accg[i][j], 0, 0, 0);
          accu[i][j] = __builtin_amdgcn_mfma_f32_16x16x32_bf16(af[i], buf[j], accu[i][j], 0, 0, 0);
        }
    }
    __syncthreads();
  }

  #pragma unroll
  for (int i = 0; i < 4; ++i)
    #pragma unroll
    for (int r = 0; r < 4; ++r) {
      int m = m0 + wm * 64 + i * 16 + qd * 4 + r;
      if (m >= M) continue;
      #pragma unroll
      for (int j = 0; j < 2; ++j) {
        float g = accg[i][j][r], u = accu[i][j][r];
        float h = g / (1.f + __expf(-g)) * u;
        int col = n0 + wn * 32 + j * 16 + l16;
        H[(size_t)(base + m) * FF + col] = f2bf(h);
      }
    }
}

// ---------------- shared gate_up + SwiGLU (NT, prefetch) ----------------
__global__ __launch_bounds__(256, 2) void gateup_shared_kernel(
    const float* __restrict__ X, const float* __restrict__ Bg,
    const float* __restrict__ Bu, ushort_t* __restrict__ H) {
  __shared__ __align__(16) ushort_t As[BM][LDK];
  __shared__ __align__(16) ushort_t Bgs[BN][LDK];
  __shared__ __align__(16) ushort_t Bus[BN][LDK];
  const int K = DH, NT = K / BK;

  int m0 = blockIdx.y * BM;
  int n0 = blockIdx.x * BN;
  int t = threadIdx.x;
  int wave = t >> 6, lane = t & 63;
  int wm = wave & 1, wn = wave >> 1;
  int qd = lane >> 4, l16 = lane & 15;
  int sr = t >> 3, sc = (t & 7) * 8;

  const float* arow[4];
  const float *bgrow[2], *burow[2];
  #pragma unroll
  for (int p = 0; p < 4; ++p)
    arow[p] = X + (size_t)(m0 + sr + 32 * p) * K + sc;
  #pragma unroll
  for (int p = 0; p < 2; ++p) {
    bgrow[p] = Bg + (size_t)(n0 + sr + 32 * p) * K + sc;
    burow[p] = Bu + (size_t)(n0 + sr + 32 * p) * K + sc;
  }

  float4 ar[4][2], bgr[2][2], bur[2][2];
  #pragma unroll
  for (int p = 0; p < 4; ++p) {
    ar[p][0] = *(const float4*)(arow[p]);
    ar[p][1] = *(const float4*)(arow[p] + 4);
  }
  #pragma unroll
  for (int p = 0; p < 2; ++p) {
    bgr[p][0] = *(const float4*)(bgrow[p]);
    bgr[p][1] = *(const float4*)(bgrow[p] + 4);
    bur[p][0] = *(const float4*)(burow[p]);
    bur[p][1] = *(const float4*)(burow[p] + 4);
  }

  f32x4 accg[4][2], accu[4][2];
  #pragma unroll
  for (int i = 0; i < 4; ++i)
    #pragma unroll
    for (int j = 0; j < 2; ++j) {
      accg[i][j] = (f32x4){0.f, 0.f, 0.f, 0.f};
      accu[i][j] = (f32x4){0.f, 0.f, 0.f, 0.f};
    }

  for (int kt = 0; kt < NT; ++kt) {
    #pragma unroll
    for (int p = 0; p < 4; ++p)
      *(uint4*)&As[sr + 32 * p][sc] = cvt8v(ar[p][0], ar[p][1]);
    #pragma unroll
    for (int p = 0; p < 2; ++p) {
      *(uint4*)&Bgs[sr + 32 * p][sc] = cvt8v(bgr[p][0], bgr[p][1]);
      *(uint4*)&Bus[sr + 32 * p][sc] = cvt8v(bur[p][0], bur[p][1]);
    }
    __syncthreads();
    if (kt + 1 < NT) {
      int ko = (kt + 1) * BK;
      #pragma unroll
      for (int p = 0; p < 4; ++p) {
        ar[p][0] = *(const float4*)(arow[p] + ko);
        ar[p][1] = *(const float4*)(arow[p] + ko + 4);
      }
      #pragma unroll
      for (int p = 0; p < 2; ++p) {
        bgr[p][0] = *(const float4*)(bgrow[p] + ko);
        bgr[p][1] = *(const float4*)(bgrow[p] + ko + 4);
        bur[p][0] = *(const float4*)(burow[p] + ko);
        bur[p][1] = *(const float4*)(burow[p] + ko + 4);
      }
    }
    #pragma unroll
    for (int ks = 0; ks < 2; ++ks) {
      int kk = ks * 32 + qd * 8;
      bf16x8 af[4], bgf[2], buf[2];
      #pragma unroll
      for (int i = 0; i < 4; ++i)
        af[i] = *(const bf16x8*)&As[wm * 64 + i * 16 + l16][kk];
      #pragma unroll
      for (int j = 0; j < 2; ++j) {
        bgf[j] = *(const bf16x8*)&Bgs[wn * 32 + j * 16 + l16][kk];
        buf[j] = *(const bf16x8*)&Bus[wn * 32 + j * 16 + l16][kk];
      }
      #pragma unroll
      for (int i = 0; i < 4; ++i)
        #pragma unroll
        for (int j = 0; j < 2; ++j) {
          accg[i][j] = __builtin_amdgcn_mfma_f32_16x16x32_bf16(af[i], bgf[j], accg[i][j], 0, 0, 0);
          accu[i][j] = __builtin_amdgcn_mfma_f32_16x16x32_bf16(af[i], buf[j], accu[i][j], 0, 0, 0);
        }
    }
    __syncthreads();
  }

  #pragma unroll
  for (int i = 0; i < 4; ++i)
    #pragma unroll
    for (int r = 0; r < 4; ++r) {
      int m = m0 + wm * 64 + i * 16 + qd * 4 + r;
      #pragma unroll
      for (int j = 0; j < 2; ++j) {
        float g = accg[i][j][r], u = accu[i][j][r];
        float h = g / (1.f + __expf(-g)) * u;
        int col = n0 + wn * 32 + j * 16 + l16;
        H[(size_t)m * SFF + col] = f2bf(h);
      }
    }
}

// ---------------- expert down: acc[tok] += w * (h @ Wd)  (prefetch) ----------------
__global__ __launch_bounds__(256, 2) void down_expert_kernel(
    const ushort_t* __restrict__ HX, const float* __restrict__ WDN,
    float* __restrict__ acc, const int* __restrict__ toks,
    const float* __restrict__ wts, const int* __restrict__ offs) {
  __shared__ __align__(16) ushort_t As[BM][LDK];
  __shared__ __align__(16) ushort_t Bs[BN][LDK];
  const int K = FF, NT = K / BK;

  int e = blockIdx.z;
  int base = offs[e], M = offs[e + 1] - base;
  int m0 = blockIdx.y * BM;
  if (m0 >= M) return;
  int n0 = blockIdx.x * BN;
  const float* W = WDN + (size_t)e * FF * DH;
  const ushort_t* A = HX + (size_t)base * K;

  int t = threadIdx.x;
  int wave = t >> 6, lane = t & 63;
  int wm = wave & 1, wn = wave >> 1;
  int qd = lane >> 4, l16 = lane & 15;
  int sr = t >> 3, sc = (t & 7) * 8;
  int tn = t & 63, tk = (t >> 6) * 16;

  const ushort_t* arow[4];
  #pragma unroll
  for (int p = 0; p < 4; ++p)
    arow[p] = A + (size_t)(m0 + sr + 32 * p) * K + sc;
  const float* wkb = W + (size_t)tk * DH + n0 + tn;

  uint4 ar[4];
  float br[16];
  #pragma unroll
  for (int p = 0; p < 4; ++p) ar[p] = *(const uint4*)(arow[p]);
  #pragma unroll
  for (int j = 0; j < 16; ++j) br[j] = wkb[(size_t)j * DH];

  f32x4 c[4][2];
  #pragma unroll
  for (int i = 0; i < 4; ++i)
    #pragma unroll
    for (int j = 0; j < 2; ++j) c[i][j] = (f32x4){0.f, 0.f, 0.f, 0.f};

  for (int kt = 0; kt < NT; ++kt) {
    #pragma unroll
    for (int p = 0; p < 4; ++p)
      *(uint4*)&As[sr + 32 * p][sc] = ar[p];
    {
      union { ushort_t u[8]; uint4 v; } b0, b1;
      #pragma unroll
      for (int j = 0; j < 8; ++j) { b0.u[j] = f2bf(br[j]); b1.u[j] = f2bf(br[8 + j]); }
      *(uint4*)&Bs[tn][tk]     = b0.v;
      *(uint4*)&Bs[tn][tk + 8] = b1.v;
    }
    __syncthreads();
    if (kt + 1 < NT) {
      int ko = (kt + 1) * BK;
      #pragma unroll
      for (int p = 0; p < 4; ++p) ar[p] = *(const uint4*)(arow[p] + ko);
      const float* wk = wkb + (size_t)ko * DH;
      #pragma unroll
      for (int j = 0; j < 16; ++j) br[j] = wk[(size_t)j * DH];
    }
    #pragma unroll
    for (int ks = 0; ks < 2; ++ks) {
      int kk = ks * 32 + qd * 8;
      bf16x8 af[4], bf[2];
      #pragma unroll
      for (int i = 0; i < 4; ++i)
        af[i] = *(const bf16x8*)&As[wm * 64 + i * 16 + l16][kk];
      #pragma unroll
      for (int j = 0; j < 2; ++j)
        bf[j] = *(const bf16x8*)&Bs[wn * 32 + j * 16 + l16][kk];
      #pragma unroll
      for (int i = 0; i < 4; ++i)
        #pragma unroll
        for (int j = 0; j < 2; ++j)
          c[i][j] = __builtin_amdgcn_mfma_f32_16x16x32_bf16(af[i], bf[j], c[i][j], 0, 0, 0);
    }
    __syncthreads();
  }

  #pragma unroll
  for (int i = 0; i < 4; ++i)
    #pragma unroll
    for (int r = 0; r < 4; ++r) {
      int m = m0 + wm * 64 + i * 16 + qd * 4 + r;
      if (m >= M) continue;
      int tok = toks[base + m];
      float w = wts[base + m];
      #pragma unroll
      for (int j = 0; j < 2; ++j) {
        int n = n0 + wn * 32 + j * 16 + l16;
        atomicAdd(&acc[(size_t)tok * DH + n], c[i][j][r] * w);
      }
    }
}

// ---------------- shared down (split-K=2, prefetch): acc += sg * (hs @ swd^T) ----------------
__global__ __launch_bounds__(256, 2) void down_shared_kernel(
    const ushort_t* __restrict__ HS, const float* __restrict__ Bp,
    float* __restrict__ acc, const float* __restrict__ sgate) {
  __shared__ __align__(16) ushort_t As[BM][LDK];
  __shared__ __align__(16) ushort_t Bs[BN][LDK];
  const int KC = SFF / 2, NT = KC / BK;   // 1408, 22

  int m0 = blockIdx.y * BM;
  int n0 = blockIdx.x * BN;
  int kb = blockIdx.z * KC;
  int t = threadIdx.x;
  int wave = t >> 6, lane = t & 63;
  int wm = wave & 1, wn = wave >> 1;
  int qd = lane >> 4, l16 = lane & 15;
  int sr = t >> 3, sc = (t & 7) * 8;

  const ushort_t* arow[4];
  const float* brow[2];
  #pragma unroll
  for (int p = 0; p < 4; ++p)
    arow[p] = HS + (size_t)(m0 + sr + 32 * p) * SFF + kb + sc;
  #pragma unroll
  for (int p = 0; p < 2; ++p)
    brow[p] = Bp + (size_t)(n0 + sr + 32 * p) * SFF + kb + sc;

  uint4 ar[4];
  float4 br[2][2];
  #pragma unroll
  for (int p = 0; p < 4; ++p) ar[p] = *(const uint4*)(arow[p]);
  #pragma unroll
  for (int p = 0; p < 2; ++p) {
    br[p][0] = *(const float4*)(brow[p]);
    br[p][1] = *(const float4*)(brow[p] + 4);
  }

  f32x4 c[4][2];
  #pragma unroll
  for (int i = 0; i < 4; ++i)
    #pragma unroll
    for (int j = 0; j < 2; ++j) c[i][j] = (f32x4){0.f, 0.f, 0.f, 0.f};

  for (int kt = 0; kt < NT; ++kt) {
    #pragma unroll
    for (int p = 0; p < 4; ++p)
      *(uint4*)&As[sr + 32 * p][sc] = ar[p];
    #pragma unroll
    for (int p = 0; p < 2; ++p)
      *(uint4*)&Bs[sr + 32 * p][sc] = cvt8v(br[p][0], br[p][1]);
    __syncthreads();
    if (kt + 1 < NT) {
      int ko = (kt + 1) * BK;
      #pragma unroll
      for (int p = 0; p < 4; ++p) ar[p] = *(const uint4*)(arow[p] + ko);
      #pragma unroll
      for (int p = 0; p < 2; ++p) {
        br[p][0] = *(const float4*)(brow[p] + ko);
        br[p][1] = *(const float4*)(brow[p] + ko + 4);
      }
    }
    #pragma unroll
    for (int ks = 0; ks < 2; ++ks) {
      int kk = ks * 32 + qd * 8;
      bf16x8 af[4], bf[2];
      #pragma unroll
      for (int i = 0; i < 4; ++i)
        af[i] = *(const bf16x8*)&As[wm * 64 + i * 16 + l16][kk];
      #pragma unroll
      for (int j = 0; j < 2; ++j)
        bf[j] = *(const bf16x8*)&Bs[wn * 32 + j * 16 + l16][kk];
      #pragma unroll
      for (int i = 0; i < 4; ++i)
        #pragma unroll
        for (int j = 0; j < 2; ++j)
          c[i][j] = __builtin_amdgcn_mfma_f32_16x16x32_bf16(af[i], bf[j], c[i][j], 0, 0, 0);
    }
    __syncthreads();
  }

  #pragma unroll
  for (int i = 0; i < 4; ++i)
    #pragma unroll
    for (int r = 0; r < 4; ++r) {
      int m = m0 + wm * 64 + i * 16 + qd * 4 + r;
      float sg = sgate[m];
      #pragma unroll
      for (int j = 0; j < 2; ++j) {
        int n = n0 + wn * 32 + j * 16 + l16;
        atomicAdd(&acc[(size_t)m * DH + n], c[i][j][r] * sg);
      }
    }
}

// ---------------- launcher ----------------
extern "C" void kernel_launch(void* const* d_in, const int* in_sizes, int n_in,
                              void* d_out, int out_size, void* d_ws, size_t ws_size,
                              hipStream_t stream) {
  const float* x    = (const float*)d_in[0];   // [2048,1024]
  const float* gw   = (const float*)d_in[1];   // [16,1024]
  const float* wgu  = (const float*)d_in[2];   // [16,1024,1024]
  const float* wdn  = (const float*)d_in[3];   // [16,512,1024]
  const float* swg  = (const float*)d_in[4];   // [2816,1024]
  const float* swu  = (const float*)d_in[5];   // [2816,1024]
  const float* swd  = (const float*)d_in[6];   // [1024,2816]
  const float* sgw  = (const float*)d_in[7];   // [1,1024]
  float* out = (float*)d_out;

  char* ws = (char*)d_ws;
  constexpr size_t OFF_ACC  = 0;                                       // 8,388,608 B
  constexpr size_t OFF_HS   = OFF_ACC + (size_t)N_TOK * DH * 4;        // +11,534,336
  constexpr size_t OFF_HX   = OFF_HS  + (size_t)N_TOK * SFF * 2;       // +4,325,376
  constexpr size_t OFF_TOK  = OFF_HX  + (size_t)4224 * FF * 2;
  constexpr size_t OFF_WTS  = OFF_TOK + 4224 * 4;
  constexpr size_t OFF_OFFS = OFF_WTS + 4224 * 4;
  constexpr size_t OFF_SEL  = OFF_OFFS + 32 * 4;
  constexpr size_t OFF_WTK  = OFF_SEL + 4096 * 4;
  constexpr size_t OFF_SG   = OFF_WTK + 4096 * 4;                      // end ~24.3 MB

  float*    acc   = (float*)(ws + OFF_ACC);
  ushort_t* hs    = (ushort_t*)(ws + OFF_HS);
  ushort_t* hx    = (ushort_t*)(ws + OFF_HX);
  int*      toks  = (int*)(ws + OFF_TOK);
  float*    wts   = (float*)(ws + OFF_WTS);
  int*      offs  = (int*)(ws + OFF_OFFS);
  int*      sel   = (int*)(ws + OFF_SEL);
  float*    wtk   = (float*)(ws + OFF_WTK);
  float*    sgate = (float*)(ws + OFF_SG);

  zero_acc_kernel<<<2048, 256, 0, stream>>>((float4*)acc);
  router_kernel<<<N_TOK / 4, 256, 0, stream>>>(x, gw, sgw, sel, wtk, sgate);
  scatter_kernel<<<1, 256, 0, stream>>>(sel, wtk, toks, wts, offs);
  gateup_expert_kernel<<<dim3(FF / BN, 16, NE), 256, 0, stream>>>(
      x, wgu, hx, toks, offs);
  gateup_shared_kernel<<<dim3(SFF / BN, N_TOK / BM, 1), 256, 0, stream>>>(
      x, swg, swu, hs);
  down_expert_kernel<<<dim3(DH / BN, 16, NE), 256, 0, stream>>>(
      hx, wdn, acc, toks, wts, offs);
  down_shared_kernel<<<dim3(DH / BN, N_TOK / BM, 2), 256, 0, stream>>>(
      hs, swd, acc, sgate);
  out_epilogue_kernel<<<2048, 256, 0, stream>>>((const float4*)acc, (float4*)out);
}